// Round 10
// baseline (215.268 us; speedup 1.0000x reference)
//
#include <hip/hip_runtime.h>
#include <hip/hip_bf16.h>
#include <math.h>

// R10: R9 (207us) with prep_k rebalanced. R9's profile: prep_k 46.6us at
// VALUBusy 4.5% — after trw/tab8/hist drain, only 128 PA/PC blocks remain
// (0.5 blocks/CU, latency-starved). Fix: PA/PC GEMM split-K x4 (512 blocks,
// K=64 chunks, f32 atomicAdd into PA/PC zeroed by init_k). prep = 1056 blocks.

#define B_ 16
#define S_ 512
#define D_ 256
#define M_ 65536
#define HALF 32768
#define NN 8192

typedef unsigned short u16;
typedef __bf16 bf16x8 __attribute__((ext_vector_type(8)));
typedef unsigned short u16x8 __attribute__((ext_vector_type(8)));
typedef unsigned short u16x4 __attribute__((ext_vector_type(4)));
typedef float f32x4 __attribute__((ext_vector_type(4)));

__device__ __forceinline__ float bf2f(u16 u) {
  union { unsigned int i; float f; } x; x.i = ((unsigned int)u) << 16; return x.f;
}
__device__ __forceinline__ u16 f2bf(float f) {
  union { float f; unsigned int i; } x; x.f = f;
  unsigned int r = x.i + 0x7FFFu + ((x.i >> 16) & 1u);  // RNE
  return (u16)(r >> 16);
}
__device__ __forceinline__ float gelu_f(float x) {
  return 0.5f * x * (1.0f + erff(x * 0.70710678118654752f));
}
__device__ __forceinline__ float ldf(const void* p, size_t i, int f32) {
  return f32 ? ((const float*)p)[i] : bf2f(((const u16*)p)[i]);
}
__device__ __forceinline__ int geti(const void* p, int i, int i64) {
  return i64 ? (int)((const long long*)p)[i] : ((const int*)p)[i];
}

__global__ __launch_bounds__(256) void diag_k(float* out, int n, float code) {
  int i = blockIdx.x * 256 + threadIdx.x;
  if (i < n) out[i] = code;
}

// ---- init: probe + zero pooled/counts/PE8+RE8/PA+PC (vectorized) ----
// gi ranges (f32x4 units): pooled 1024 | counts 2048 | PE8+RE8 2048 | PA+PC 131072
__global__ __launch_bounds__(256) void init_k(float* pooled, int* counts,
    float* PE8, float* PA, const unsigned int* lng,
    const int* a0, const int* a1, int* flags) {
  if (blockIdx.x == 0 && threadIdx.x == 0) {
    flags[0] = (lng[0] == 0x3F800000u) ? 1 : 0;
    int z = 0;
    for (int j = 1; j < 12; j += 2) z += (a0[j] == 0);
    for (int j = 1; j < 12; j += 2) z += (a1[j] == 0);
    flags[1] = (z >= 10) ? 1 : 0;
  }
  const int gi = blockIdx.x * 256 + threadIdx.x;
  const f32x4 z4 = {0.f, 0.f, 0.f, 0.f};
  if (gi < 1024) ((f32x4*)pooled)[gi] = z4;
  else if (gi < 3072) ((f32x4*)counts)[gi - 1024] = z4;
  else if (gi < 5120) ((f32x4*)PE8)[gi - 3072] = z4;        // PE8+RE8 contiguous
  else if (gi < 136192) ((f32x4*)PA)[gi - 5120] = z4;       // PA+PC contiguous
}

__device__ __forceinline__ int msg_dst(const void* a0, const void* a1,
                                       const void* pred, int vm, int fI) {
  const bool fwd = vm < HALF;
  const int e = fwd ? vm : vm - HALF;
  const int p = geti(pred, e, fI);
  const int b = e >> 11;
  if (fwd) return b * 512 + ((p == 1) ? geti(a0, e, fI) : geti(a1, e, fI));
  return (p != 0 && p != 1) ? (b * 512 + geti(a0, e, fI)) : -1;
}

// ---- prep: trw (0..31) | pa splitK (32..543) | tab8 splitK (544..799) | hist (800..1055)
__global__ __launch_bounds__(256) void prep_k(
    const void* __restrict__ a0, const void* __restrict__ a1,
    const void* __restrict__ pred, const void* __restrict__ W2,
    const void* __restrict__ pos, const void* __restrict__ W1,
    const void* __restrict__ pe, const void* __restrict__ re,
    u16* __restrict__ W2T, float* __restrict__ PA, float* __restrict__ PC,
    float* __restrict__ PE8, float* __restrict__ RE8,
    int* __restrict__ counts, const int* __restrict__ flags)
{
  __shared__ alignas(16) char smem[10240];
  const int bid = blockIdx.x;
  const int tid = threadIdx.x;
  const int fF = flags[0], fI = flags[1];

  if (bid < 32) {
    // W2 (512x256) -> W2T[n*512+k] via 64x64 LDS tile
    u16 (*tile)[65] = (u16(*)[65])smem;
    const int tk = (bid >> 2) * 64, tn = (bid & 3) * 64;
    const int ln = tid & 63, l4 = tid >> 6;
    for (int kk = 0; kk < 64; kk += 4) {
      const int k = tk + kk + l4;
      tile[kk + l4][ln] = fF ? f2bf(((const float*)W2)[(size_t)k * 256 + tn + ln])
                             : ((const u16*)W2)[(size_t)k * 256 + tn + ln];
    }
    __syncthreads();
    const int lk = tid & 63;
    for (int nn = 0; nn < 64; nn += 4)
      W2T[(size_t)(tn + nn + l4) * 512 + tk + lk] = tile[lk][nn + l4];
  } else if (bid < 544) {
    // PA/PC split-K: 2 mats x 64 tiles (64x64) x 4 k-chunks of 64
    float (*As)[68] = (float(*)[68])smem;
    float (*Bs)[68] = (float(*)[68])(smem + 16 * 68 * 4);
    const int b2i = bid - 32;
    const int z = b2i >> 8;               // 0=PA, 1=PC
    const int rem = b2i & 255;
    const int kc = rem >> 6;              // k-chunk 0..3 (64 k each)
    const int t = rem & 63;
    const int m0 = (t >> 3) * 64, n0 = (t & 7) * 64;
    const int koff = (z ? 512 : 0) + kc * 64;   // W1 row base
    const int aoff = kc * 64;                   // pos col base
    float* dst = z ? PC : PA;
    const int ty = tid >> 4, tx = tid & 15;
    const int sm = tid & 63, sg = tid >> 6;
    float acc[4][4] = {};
    for (int k0 = 0; k0 < 64; k0 += 16) {
      const int ko = aoff + k0 + sg * 4;
      float av[4];
      if (fF) {
        f32x4 v = *(const f32x4*)((const float*)pos + (size_t)(m0 + sm) * 256 + ko);
        av[0] = v[0]; av[1] = v[1]; av[2] = v[2]; av[3] = v[3];
      } else {
        u16x4 v = *(const u16x4*)((const u16*)pos + (size_t)(m0 + sm) * 256 + ko);
        av[0] = bf2f(v[0]); av[1] = bf2f(v[1]); av[2] = bf2f(v[2]); av[3] = bf2f(v[3]);
      }
      #pragma unroll
      for (int c = 0; c < 4; ++c) As[sg * 4 + c][sm] = av[c];
      #pragma unroll
      for (int c = 0; c < 4; ++c) {
        const int kk = sg * 4 + c;
        Bs[kk][sm] = ldf(W1, (size_t)(koff + k0 + kk) * 512 + n0 + sm, fF);
      }
      __syncthreads();
      #pragma unroll
      for (int kk = 0; kk < 16; ++kk) {
        f32x4 a4 = *(const f32x4*)&As[kk][ty * 4];
        f32x4 b4 = *(const f32x4*)&Bs[kk][tx * 4];
        #pragma unroll
        for (int i = 0; i < 4; ++i)
          #pragma unroll
          for (int j = 0; j < 4; ++j) acc[i][j] += a4[i] * b4[j];
      }
      __syncthreads();
    }
    #pragma unroll
    for (int i = 0; i < 4; ++i)
      #pragma unroll
      for (int j = 0; j < 4; ++j)
        atomicAdd(&dst[(size_t)(m0 + ty * 4 + i) * 512 + n0 + tx * 4 + j],
                  acc[i][j]);
  } else if (bid < 800) {
    // PE8/RE8 split-K: 16 rows x 16 k-chunks of 16
    const int b3 = bid - 544;
    const int r = b3 & 15, kc = b3 >> 4;
    const bool ispe = r < 8;
    const void* src = ispe ? pe : re;
    const int row = ispe ? r : r - 8;
    const int wrow0 = (ispe ? 256 : 512) + kc * 16;
    float* dst = (ispe ? PE8 : RE8) + (size_t)row * 512;
    const int n1 = tid, n2 = tid + 256;
    float s1 = 0.f, s2 = 0.f;
    #pragma unroll
    for (int k = 0; k < 16; ++k) {
      const float av = ldf(src, (size_t)row * 256 + kc * 16 + k, fF);
      s1 += av * ldf(W1, (size_t)(wrow0 + k) * 512 + n1, fF);
      s2 += av * ldf(W1, (size_t)(wrow0 + k) * 512 + n2, fF);
    }
    atomicAdd(&dst[n1], s1);
    atomicAdd(&dst[n2], s2);
  } else if (bid < 1056) {
    const int vm = (bid - 800) * 256 + tid;
    const int d = msg_dst(a0, a1, pred, vm, fI);
    if (d >= 0) atomicAdd(&counts[d], 1);
  }
}

__global__ __launch_bounds__(256) void scan_k(const int* __restrict__ counts,
    int* __restrict__ offsets, int* __restrict__ cursor) {
  __shared__ int part[256];
  const int t = threadIdx.x;
  int s = 0;
  for (int i = 0; i < 32; ++i) s += counts[t * 32 + i];
  part[t] = s;
  __syncthreads();
  if (t == 0) {
    int run = 0;
    for (int i = 0; i < 256; ++i) { int v = part[i]; part[i] = run; run += v; }
  }
  __syncthreads();
  int run = part[t];
  for (int i = 0; i < 32; ++i) {
    offsets[t * 32 + i] = run; cursor[t * 32 + i] = run;
    run += counts[t * 32 + i];
  }
}

// fill: packed rec = i0 | p<<9 | sel<<12 | i2<<13
__global__ __launch_bounds__(256) void fill_k(const void* a0, const void* a1,
    const void* pred, const void* role, int* __restrict__ cursor,
    int* __restrict__ plist, const int* __restrict__ flags) {
  const int fI = flags[1];
  const int vm = blockIdx.x * 256 + threadIdx.x;
  const bool fwd = vm < HALF;
  const int e = fwd ? vm : vm - HALF;
  const int p = geti(pred, e, fI);
  const int b = e >> 11;
  int dst, i0, sel, i2;
  if (fwd) {
    const int v0 = geti(a0, e, fI), v1 = geti(a1, e, fI);
    i0 = v0;
    if (p == 1) { sel = 1; i2 = geti(role, e, fI) + 1; dst = b * 512 + v0; }
    else        { sel = 0; i2 = v1;                    dst = b * 512 + v1; }
  } else {
    if (p == 0 || p == 1) return;
    const int v0 = geti(a0, e, fI), v1 = geti(a1, e, fI);
    i0 = v1; sel = 0; i2 = v0; dst = b * 512 + v0;
  }
  const int rec = i0 | (p << 9) | (sel << 12) | (i2 << 13);
  plist[atomicAdd(&cursor[dst], 1)] = rec;
}

// ---- nodesum: HSb[node] = bf16( sum_edges gelu(PA[i0]+PE8[p]+X2[i2]+b1) ) ----
__global__ __launch_bounds__(256) void nodesum_k(
    const float* __restrict__ PA, const float* __restrict__ PC,
    const float* __restrict__ PE8, const float* __restrict__ RE8,
    const void* __restrict__ b1,
    const int* __restrict__ plist, const int* __restrict__ offsets,
    const int* __restrict__ counts, u16* __restrict__ HSb,
    const int* __restrict__ flags)
{
  const int fF = flags[0];
  const int node = blockIdx.x * 4 + (threadIdx.x >> 6);
  const int lane = threadIdx.x & 63;
  const int c0 = lane * 8;
  const int base = offsets[node], cnt = counts[node];
  float b1v[8];
  #pragma unroll
  for (int q = 0; q < 8; ++q) b1v[q] = ldf(b1, c0 + q, fF);
  float acc[8] = {};
  for (int e = 0; e < cnt; ++e) {
    const int rec = plist[base + e];
    const int i0 = rec & 511, p = (rec >> 9) & 7;
    const int sel = (rec >> 12) & 1, i2 = (rec >> 13) & 511;
    const f32x4* r0 = (const f32x4*)(PA + (size_t)i0 * 512 + c0);
    const f32x4* r1 = (const f32x4*)(PE8 + (size_t)p * 512 + c0);
    const f32x4* r2 = (const f32x4*)((sel ? RE8 : PC) + (size_t)i2 * 512 + c0);
    f32x4 x0 = r0[0], x1 = r0[1];
    f32x4 y0 = r1[0], y1 = r1[1];
    f32x4 z0 = r2[0], z1 = r2[1];
    #pragma unroll
    for (int q = 0; q < 4; ++q) {
      acc[q]     += gelu_f(x0[q] + y0[q] + z0[q] + b1v[q]);
      acc[q + 4] += gelu_f(x1[q] + y1[q] + z1[q] + b1v[q + 4]);
    }
  }
  u16x8 o;
  #pragma unroll
  for (int q = 0; q < 8; ++q) o[q] = f2bf(acc[q]);
  *(u16x8*)&HSb[(size_t)node * 512 + c0] = o;
}

// ---- gemm2 MFMA: agg = HSb @ W2 + cnt*b2 + pos[s] ----
__global__ __launch_bounds__(256) void gemm2_k(
    const u16* __restrict__ HSb, const u16* __restrict__ W2T,
    const void* __restrict__ b2, const void* __restrict__ pos,
    const int* __restrict__ counts, float* __restrict__ agg,
    const int* __restrict__ flags)
{
  const int fF = flags[0];
  __shared__ u16 As[64 * 40];
  __shared__ u16 Bs[64 * 40];
  const int tid = threadIdx.x;
  const int lane = tid & 63;
  const int wave = tid >> 6;
  const int wm = (wave & 1) * 32;
  const int wn = (wave >> 1) * 32;
  const int r = tid >> 2;
  const int c8 = (tid & 3) * 8;
  const int n0 = blockIdx.y * 64;

  const u16* asrc0 = HSb + (size_t)(blockIdx.x * 64 + r) * 512 + c8;
  const u16* bsrc  = W2T + (size_t)(n0 + r) * 512 + c8;

  f32x4 acc[2][2] = {{{0.f,0.f,0.f,0.f},{0.f,0.f,0.f,0.f}},
                     {{0.f,0.f,0.f,0.f},{0.f,0.f,0.f,0.f}}};
  const int lrow = lane & 15;
  const int qk = (lane >> 4) * 8;

  for (int kt = 0; kt < 16; ++kt) {
    const int k0 = kt * 32;
    u16x8 av = *(const u16x8*)(asrc0 + k0);
    u16x8 bv = *(const u16x8*)(bsrc + k0);
    *(u16x8*)&As[r * 40 + c8] = av;
    *(u16x8*)&Bs[r * 40 + c8] = bv;
    __syncthreads();
    bf16x8 af0 = *(const bf16x8*)&As[(wm + lrow) * 40 + qk];
    bf16x8 af1 = *(const bf16x8*)&As[(wm + 16 + lrow) * 40 + qk];
    bf16x8 bf0 = *(const bf16x8*)&Bs[(wn + lrow) * 40 + qk];
    bf16x8 bf1 = *(const bf16x8*)&Bs[(wn + 16 + lrow) * 40 + qk];
    acc[0][0] = __builtin_amdgcn_mfma_f32_16x16x32_bf16(af0, bf0, acc[0][0], 0, 0, 0);
    acc[0][1] = __builtin_amdgcn_mfma_f32_16x16x32_bf16(af0, bf1, acc[0][1], 0, 0, 0);
    acc[1][0] = __builtin_amdgcn_mfma_f32_16x16x32_bf16(af1, bf0, acc[1][0], 0, 0, 0);
    acc[1][1] = __builtin_amdgcn_mfma_f32_16x16x32_bf16(af1, bf1, acc[1][1], 0, 0, 0);
    __syncthreads();
  }
  const int quad = lane >> 4;
  for (int j = 0; j < 2; ++j) {
    const int col = n0 + wn + j * 16 + lrow;
    const float b2v = ldf(b2, col, fF);
    for (int i = 0; i < 2; ++i) {
      const int row = blockIdx.x * 64 + wm + i * 16 + quad * 4;
      for (int rg = 0; rg < 4; ++rg) {
        const int s = (row + rg) & 511;
        agg[(size_t)(row + rg) * 256 + col] =
            acc[i][j][rg] + (float)counts[row + rg] * b2v
            + ldf(pos, (size_t)s * 256 + col, fF);
      }
    }
  }
}

// ---- ln_pool ----
__global__ __launch_bounds__(256) void ln_pool_k(
    const float* __restrict__ agg, const void* __restrict__ g,
    const void* __restrict__ bta, float* __restrict__ pooled,
    const int* __restrict__ flags)
{
  const int fF = flags[0];
  __shared__ float red[4][256];
  const int b = blockIdx.x >> 3, c = blockIdx.x & 7;
  const int w = threadIdx.x >> 6, lane = threadIdx.x & 63;
  const int d0 = lane * 4;
  float g4[4], bt4[4];
  #pragma unroll
  for (int i = 0; i < 4; ++i) {
    g4[i] = ldf(g, d0 + i, fF);
    bt4[i] = ldf(bta, d0 + i, fF);
  }
  float pacc[4] = {};
  for (int r = 0; r < 16; ++r) {
    const int row = b * 512 + c * 64 + w * 16 + r;
    f32x4 a = *(const f32x4*)&agg[(size_t)row * 256 + d0];
    float sum = a[0] + a[1] + a[2] + a[3];
    float sq = a[0]*a[0] + a[1]*a[1] + a[2]*a[2] + a[3]*a[3];
    for (int o = 32; o; o >>= 1) {
      sum += __shfl_xor(sum, o, 64);
      sq  += __shfl_xor(sq, o, 64);
    }
    const float mean = sum * (1.0f / 256.0f);
    const float var = sq * (1.0f / 256.0f) - mean * mean;
    const float rs = rsqrtf(var + 1e-5f);
    #pragma unroll
    for (int i = 0; i < 4; ++i)
      pacc[i] += (a[i] - mean) * rs * g4[i] + bt4[i];
  }
  #pragma unroll
  for (int i = 0; i < 4; ++i) red[w][d0 + i] = pacc[i];
  __syncthreads();
  if (w == 0) {
    #pragma unroll
    for (int i = 0; i < 4; ++i) {
      const float v = red[0][d0+i] + red[1][d0+i] + red[2][d0+i] + red[3][d0+i];
      atomicAdd(&pooled[b * 256 + d0 + i], v * (1.0f / 512.0f));
    }
  }
}

// ---- head MLPs ----
__global__ __launch_bounds__(256) void mlp1_k(const float* __restrict__ pooled,
    const void* __restrict__ Wl1, const void* __restrict__ bl1,
    float* __restrict__ hid, const int* __restrict__ flags)
{
  const int fF = flags[0];
  const int gid = blockIdx.x * 256 + threadIdx.x;
  const int oid = gid >> 2, sub = gid & 3;
  const int b = oid >> 9, n = oid & 511;
  const float* pr = pooled + b * 256;
  float s = 0.f;
  for (int i = 0; i < 64; ++i) {
    const int k = sub + 4 * i;
    s += pr[k] * ldf(Wl1, (size_t)k * 512 + n, fF);
  }
  s += __shfl_xor(s, 1, 64);
  s += __shfl_xor(s, 2, 64);
  if (sub == 0) hid[oid] = gelu_f(s + ldf(bl1, n, fF));
}
__global__ __launch_bounds__(256) void mlp2_k(const float* __restrict__ hid,
    const void* __restrict__ Wl2, const void* __restrict__ bl2,
    float* __restrict__ outp, const int* __restrict__ flags)
{
  const int fF = flags[0];
  const int gid = blockIdx.x * 256 + threadIdx.x;
  const int oid = gid >> 3, sub = gid & 7;
  const int b = oid >> 9, n = oid & 511;
  const float* hr = hid + b * 512;
  float s = 0.f;
  for (int i = 0; i < 64; ++i) {
    const int k = sub + 8 * i;
    s += hr[k] * ldf(Wl2, (size_t)k * 512 + n, fF);
  }
  s += __shfl_xor(s, 1, 64);
  s += __shfl_xor(s, 2, 64);
  s += __shfl_xor(s, 4, 64);
  if (sub == 0) outp[oid] = s + ldf(bl2, n, fF);
}

extern "C" void kernel_launch(void* const* d_in, const int* in_sizes, int n_in,
                              void* d_out, int out_size, void* d_ws, size_t ws_size,
                              hipStream_t stream)
{
  const void* a0   = d_in[0];
  const void* a1   = d_in[1];
  const void* pred = d_in[2];
  const void* role = d_in[3];
  const void* pos  = d_in[5];
  const void* pe   = d_in[6];
  const void* re   = d_in[7];
  const void* W1   = d_in[8];
  const void* b1   = d_in[9];
  const void* W2   = d_in[10];
  const void* b2   = d_in[11];
  const void* lng  = d_in[12];
  const void* lnb  = d_in[13];
  const void* Wl1  = d_in[14];
  const void* bl1  = d_in[15];
  const void* Wl2  = d_in[16];
  const void* bl2  = d_in[17];

  static const int EXP[18] = {32768, 32768, 32768, 32768, 1,
                              131072, 2048, 2048, 393216, 512,
                              131072, 256, 256, 256, 131072, 512, 262144, 512};
  long long code = 0;
  if (n_in != 18) code = 1000000 + (long long)n_in * 16384;
  if (!code)
    for (int i = 0; i < 18; ++i)
      if (in_sizes[i] != EXP[i]) { code = 3000000 + (long long)i * 65536; break; }
  if (!code && out_size != 8192) code = 9000000;

  size_t o = 0;
  const size_t offFlags = o; o += 256;
  const size_t offPool  = o; o += 16384;
  const size_t offHid   = o; o += 32768;
  const size_t offW2T   = o; o += (size_t)256 * 512 * 2;
  const size_t offPA    = o; o += (size_t)512 * 512 * 4;
  const size_t offPC    = o; o += (size_t)512 * 512 * 4;   // contiguous with PA
  const size_t offPE8   = o; o += (size_t)8 * 512 * 4;
  const size_t offRE8   = o; o += (size_t)8 * 512 * 4;     // contiguous with PE8
  const size_t offCnt   = o; o += (size_t)NN * 4;
  const size_t offOff   = o; o += (size_t)NN * 4;
  const size_t offCur   = o; o += (size_t)NN * 4;
  const size_t offList  = o; o += (size_t)M_ * 4;
  const size_t offHSb   = o; o += (size_t)NN * 512 * 2;
  const size_t offAgg   = o; o += (size_t)NN * 256 * 4;
  if (!code && o > ws_size)
    code = 5000000 + (long long)((ws_size >> 20) & 255) * 32768;
  if (code) {
    diag_k<<<(out_size + 255) / 256, 256, 0, stream>>>((float*)d_out, out_size, (float)code);
    return;
  }

  char* w = (char*)d_ws;
  int* flags    = (int*)(w + offFlags);
  float* pooled = (float*)(w + offPool);
  float* hid    = (float*)(w + offHid);
  u16* W2T      = (u16*)(w + offW2T);
  float* PA     = (float*)(w + offPA);
  float* PC     = (float*)(w + offPC);
  float* PE8    = (float*)(w + offPE8);
  float* RE8    = (float*)(w + offRE8);
  int* counts   = (int*)(w + offCnt);
  int* offsets  = (int*)(w + offOff);
  int* cursor   = (int*)(w + offCur);
  int* plist    = (int*)(w + offList);
  u16* HSb      = (u16*)(w + offHSb);
  float* agg    = (float*)(w + offAgg);

  init_k<<<532, 256, 0, stream>>>(pooled, counts, PE8, PA,
                                  (const unsigned int*)lng,
                                  (const int*)a0, (const int*)a1, flags);
  prep_k<<<1056, 256, 0, stream>>>(a0, a1, pred, W2, pos, W1, pe, re,
                                   W2T, PA, PC, PE8, RE8, counts, flags);
  scan_k<<<1, 256, 0, stream>>>(counts, offsets, cursor);
  fill_k<<<M_ / 256, 256, 0, stream>>>(a0, a1, pred, role, cursor, plist, flags);
  nodesum_k<<<NN / 4, 256, 0, stream>>>(PA, PC, PE8, RE8, b1,
                                        plist, offsets, counts, HSb, flags);
  gemm2_k<<<dim3(NN / 64, 4), 256, 0, stream>>>(HSb, W2T, b2, pos, counts, agg, flags);
  ln_pool_k<<<128, 256, 0, stream>>>(agg, lng, lnb, pooled, flags);
  mlp1_k<<<128, 256, 0, stream>>>(pooled, Wl1, bl1, hid, flags);
  mlp2_k<<<256, 256, 0, stream>>>(hid, Wl2, bl2, (float*)d_out, flags);
}

// Round 11
// 186.321 us; speedup vs baseline: 1.1554x; 1.1554x over previous
//
#include <hip/hip_runtime.h>
#include <hip/hip_bf16.h>
#include <math.h>

// R11: R10 post-mortem — split-K atomics for PA/PC cost 34.8MB of memory-side
// RMW (WRITE_SIZE 4.1->34.8MB), prep_k stayed 44.7us. Revert to no-atomic
// full-K PA/PC tiles and attack the REAL problem (16-iter serial latency chain
// at 1 block/CU) with register prefetch (load k+1 while computing k). Same
// prefetch added to gemm2_k. init_k back to 20 blocks.

#define B_ 16
#define S_ 512
#define D_ 256
#define M_ 65536
#define HALF 32768
#define NN 8192

typedef unsigned short u16;
typedef __bf16 bf16x8 __attribute__((ext_vector_type(8)));
typedef unsigned short u16x8 __attribute__((ext_vector_type(8)));
typedef unsigned short u16x4 __attribute__((ext_vector_type(4)));
typedef float f32x4 __attribute__((ext_vector_type(4)));

__device__ __forceinline__ float bf2f(u16 u) {
  union { unsigned int i; float f; } x; x.i = ((unsigned int)u) << 16; return x.f;
}
__device__ __forceinline__ u16 f2bf(float f) {
  union { float f; unsigned int i; } x; x.f = f;
  unsigned int r = x.i + 0x7FFFu + ((x.i >> 16) & 1u);  // RNE
  return (u16)(r >> 16);
}
__device__ __forceinline__ float gelu_f(float x) {
  return 0.5f * x * (1.0f + erff(x * 0.70710678118654752f));
}
__device__ __forceinline__ float ldf(const void* p, size_t i, int f32) {
  return f32 ? ((const float*)p)[i] : bf2f(((const u16*)p)[i]);
}
__device__ __forceinline__ int geti(const void* p, int i, int i64) {
  return i64 ? (int)((const long long*)p)[i] : ((const int*)p)[i];
}

__global__ __launch_bounds__(256) void diag_k(float* out, int n, float code) {
  int i = blockIdx.x * 256 + threadIdx.x;
  if (i < n) out[i] = code;
}

// ---- init: probe + zero pooled/counts/PE8+RE8 (f32x4), 20 blocks ----
__global__ __launch_bounds__(256) void init_k(float* pooled, int* counts,
    float* PE8, const unsigned int* lng,
    const int* a0, const int* a1, int* flags) {
  if (blockIdx.x == 0 && threadIdx.x == 0) {
    flags[0] = (lng[0] == 0x3F800000u) ? 1 : 0;
    int z = 0;
    for (int j = 1; j < 12; j += 2) z += (a0[j] == 0);
    for (int j = 1; j < 12; j += 2) z += (a1[j] == 0);
    flags[1] = (z >= 10) ? 1 : 0;
  }
  const int gi = blockIdx.x * 256 + threadIdx.x;
  const f32x4 z4 = {0.f, 0.f, 0.f, 0.f};
  if (gi < 1024) ((f32x4*)pooled)[gi] = z4;
  else if (gi < 3072) ((f32x4*)counts)[gi - 1024] = z4;
  else if (gi < 5120) ((f32x4*)PE8)[gi - 3072] = z4;   // PE8+RE8 contiguous
}

__device__ __forceinline__ int msg_dst(const void* a0, const void* a1,
                                       const void* pred, int vm, int fI) {
  const bool fwd = vm < HALF;
  const int e = fwd ? vm : vm - HALF;
  const int p = geti(pred, e, fI);
  const int b = e >> 11;
  if (fwd) return b * 512 + ((p == 1) ? geti(a0, e, fI) : geti(a1, e, fI));
  return (p != 0 && p != 1) ? (b * 512 + geti(a0, e, fI)) : -1;
}

// ---- prep: trw (0..31) | pa prefetch (32..159) | tab8 splitK (160..415) | hist (416..671)
__global__ __launch_bounds__(256) void prep_k(
    const void* __restrict__ a0, const void* __restrict__ a1,
    const void* __restrict__ pred, const void* __restrict__ W2,
    const void* __restrict__ pos, const void* __restrict__ W1,
    const void* __restrict__ pe, const void* __restrict__ re,
    u16* __restrict__ W2T, float* __restrict__ PA, float* __restrict__ PC,
    float* __restrict__ PE8, float* __restrict__ RE8,
    int* __restrict__ counts, const int* __restrict__ flags)
{
  __shared__ alignas(16) char smem[10240];
  const int bid = blockIdx.x;
  const int tid = threadIdx.x;
  const int fF = flags[0], fI = flags[1];

  if (bid < 32) {
    // W2 (512x256) -> W2T[n*512+k] via 64x64 LDS tile
    u16 (*tile)[65] = (u16(*)[65])smem;
    const int tk = (bid >> 2) * 64, tn = (bid & 3) * 64;
    const int ln = tid & 63, l4 = tid >> 6;
    for (int kk = 0; kk < 64; kk += 4) {
      const int k = tk + kk + l4;
      tile[kk + l4][ln] = fF ? f2bf(((const float*)W2)[(size_t)k * 256 + tn + ln])
                             : ((const u16*)W2)[(size_t)k * 256 + tn + ln];
    }
    __syncthreads();
    const int lk = tid & 63;
    for (int nn = 0; nn < 64; nn += 4)
      W2T[(size_t)(tn + nn + l4) * 512 + tk + lk] = tile[lk][nn + l4];
  } else if (bid < 160) {
    // PA/PC: pos @ W1-block, 64x64 tile, K=256, BK=16, REGISTER PREFETCH
    float (*As)[68] = (float(*)[68])smem;
    float (*Bs)[68] = (float(*)[68])(smem + 16 * 68 * 4);
    const int b2i = bid - 32;
    const int z = b2i >> 6, rem = b2i & 63;
    const int m0 = (rem >> 3) * 64, n0 = (rem & 7) * 64;
    const int koff = z ? 512 : 0;
    float* dst = z ? PC : PA;
    const int ty = tid >> 4, tx = tid & 15;
    const int sm = tid & 63, sg = tid >> 6;

    float avc[4], bvc[4];
    // preload k0 = 0
    {
      const int ko = sg * 4;
      if (fF) {
        f32x4 v = *(const f32x4*)((const float*)pos + (size_t)(m0 + sm) * 256 + ko);
        avc[0] = v[0]; avc[1] = v[1]; avc[2] = v[2]; avc[3] = v[3];
      } else {
        u16x4 v = *(const u16x4*)((const u16*)pos + (size_t)(m0 + sm) * 256 + ko);
        avc[0] = bf2f(v[0]); avc[1] = bf2f(v[1]); avc[2] = bf2f(v[2]); avc[3] = bf2f(v[3]);
      }
      #pragma unroll
      for (int c = 0; c < 4; ++c)
        bvc[c] = ldf(W1, (size_t)(koff + sg * 4 + c) * 512 + n0 + sm, fF);
    }
    float acc[4][4] = {};
    for (int k0 = 0; k0 < 256; k0 += 16) {
      #pragma unroll
      for (int c = 0; c < 4; ++c) As[sg * 4 + c][sm] = avc[c];
      #pragma unroll
      for (int c = 0; c < 4; ++c) Bs[sg * 4 + c][sm] = bvc[c];
      __syncthreads();
      // prefetch next k-tile while computing this one (clamped; last is unused)
      const int k1 = (k0 + 16 < 256) ? k0 + 16 : 0;
      float avn[4], bvn[4];
      {
        const int ko = k1 + sg * 4;
        if (fF) {
          f32x4 v = *(const f32x4*)((const float*)pos + (size_t)(m0 + sm) * 256 + ko);
          avn[0] = v[0]; avn[1] = v[1]; avn[2] = v[2]; avn[3] = v[3];
        } else {
          u16x4 v = *(const u16x4*)((const u16*)pos + (size_t)(m0 + sm) * 256 + ko);
          avn[0] = bf2f(v[0]); avn[1] = bf2f(v[1]); avn[2] = bf2f(v[2]); avn[3] = bf2f(v[3]);
        }
        #pragma unroll
        for (int c = 0; c < 4; ++c)
          bvn[c] = ldf(W1, (size_t)(koff + k1 + sg * 4 + c) * 512 + n0 + sm, fF);
      }
      #pragma unroll
      for (int kk = 0; kk < 16; ++kk) {
        f32x4 a4 = *(const f32x4*)&As[kk][ty * 4];
        f32x4 b4 = *(const f32x4*)&Bs[kk][tx * 4];
        #pragma unroll
        for (int i = 0; i < 4; ++i)
          #pragma unroll
          for (int j = 0; j < 4; ++j) acc[i][j] += a4[i] * b4[j];
      }
      __syncthreads();
      #pragma unroll
      for (int c = 0; c < 4; ++c) { avc[c] = avn[c]; bvc[c] = bvn[c]; }
    }
    #pragma unroll
    for (int i = 0; i < 4; ++i)
      #pragma unroll
      for (int j = 0; j < 4; ++j)
        dst[(size_t)(m0 + ty * 4 + i) * 512 + n0 + tx * 4 + j] = acc[i][j];
  } else if (bid < 416) {
    // PE8/RE8 split-K: 16 rows x 16 k-chunks of 16 (tiny output -> atomics OK)
    const int b3 = bid - 160;
    const int r = b3 & 15, kc = b3 >> 4;
    const bool ispe = r < 8;
    const void* src = ispe ? pe : re;
    const int row = ispe ? r : r - 8;
    const int wrow0 = (ispe ? 256 : 512) + kc * 16;
    float* dst = (ispe ? PE8 : RE8) + (size_t)row * 512;
    const int n1 = tid, n2 = tid + 256;
    float s1 = 0.f, s2 = 0.f;
    #pragma unroll
    for (int k = 0; k < 16; ++k) {
      const float av = ldf(src, (size_t)row * 256 + kc * 16 + k, fF);
      s1 += av * ldf(W1, (size_t)(wrow0 + k) * 512 + n1, fF);
      s2 += av * ldf(W1, (size_t)(wrow0 + k) * 512 + n2, fF);
    }
    atomicAdd(&dst[n1], s1);
    atomicAdd(&dst[n2], s2);
  } else if (bid < 672) {
    const int vm = (bid - 416) * 256 + tid;
    const int d = msg_dst(a0, a1, pred, vm, fI);
    if (d >= 0) atomicAdd(&counts[d], 1);
  }
}

__global__ __launch_bounds__(256) void scan_k(const int* __restrict__ counts,
    int* __restrict__ offsets, int* __restrict__ cursor) {
  __shared__ int part[256];
  const int t = threadIdx.x;
  int s = 0;
  for (int i = 0; i < 32; ++i) s += counts[t * 32 + i];
  part[t] = s;
  __syncthreads();
  if (t == 0) {
    int run = 0;
    for (int i = 0; i < 256; ++i) { int v = part[i]; part[i] = run; run += v; }
  }
  __syncthreads();
  int run = part[t];
  for (int i = 0; i < 32; ++i) {
    offsets[t * 32 + i] = run; cursor[t * 32 + i] = run;
    run += counts[t * 32 + i];
  }
}

// fill: packed rec = i0 | p<<9 | sel<<12 | i2<<13
__global__ __launch_bounds__(256) void fill_k(const void* a0, const void* a1,
    const void* pred, const void* role, int* __restrict__ cursor,
    int* __restrict__ plist, const int* __restrict__ flags) {
  const int fI = flags[1];
  const int vm = blockIdx.x * 256 + threadIdx.x;
  const bool fwd = vm < HALF;
  const int e = fwd ? vm : vm - HALF;
  const int p = geti(pred, e, fI);
  const int b = e >> 11;
  int dst, i0, sel, i2;
  if (fwd) {
    const int v0 = geti(a0, e, fI), v1 = geti(a1, e, fI);
    i0 = v0;
    if (p == 1) { sel = 1; i2 = geti(role, e, fI) + 1; dst = b * 512 + v0; }
    else        { sel = 0; i2 = v1;                    dst = b * 512 + v1; }
  } else {
    if (p == 0 || p == 1) return;
    const int v0 = geti(a0, e, fI), v1 = geti(a1, e, fI);
    i0 = v1; sel = 0; i2 = v0; dst = b * 512 + v0;
  }
  const int rec = i0 | (p << 9) | (sel << 12) | (i2 << 13);
  plist[atomicAdd(&cursor[dst], 1)] = rec;
}

// ---- nodesum: HSb[node] = bf16( sum_edges gelu(PA[i0]+PE8[p]+X2[i2]+b1) ) ----
__global__ __launch_bounds__(256) void nodesum_k(
    const float* __restrict__ PA, const float* __restrict__ PC,
    const float* __restrict__ PE8, const float* __restrict__ RE8,
    const void* __restrict__ b1,
    const int* __restrict__ plist, const int* __restrict__ offsets,
    const int* __restrict__ counts, u16* __restrict__ HSb,
    const int* __restrict__ flags)
{
  const int fF = flags[0];
  const int node = blockIdx.x * 4 + (threadIdx.x >> 6);
  const int lane = threadIdx.x & 63;
  const int c0 = lane * 8;
  const int base = offsets[node], cnt = counts[node];
  float b1v[8];
  #pragma unroll
  for (int q = 0; q < 8; ++q) b1v[q] = ldf(b1, c0 + q, fF);
  float acc[8] = {};
  for (int e = 0; e < cnt; ++e) {
    const int rec = plist[base + e];
    const int i0 = rec & 511, p = (rec >> 9) & 7;
    const int sel = (rec >> 12) & 1, i2 = (rec >> 13) & 511;
    const f32x4* r0 = (const f32x4*)(PA + (size_t)i0 * 512 + c0);
    const f32x4* r1 = (const f32x4*)(PE8 + (size_t)p * 512 + c0);
    const f32x4* r2 = (const f32x4*)((sel ? RE8 : PC) + (size_t)i2 * 512 + c0);
    f32x4 x0 = r0[0], x1 = r0[1];
    f32x4 y0 = r1[0], y1 = r1[1];
    f32x4 z0 = r2[0], z1 = r2[1];
    #pragma unroll
    for (int q = 0; q < 4; ++q) {
      acc[q]     += gelu_f(x0[q] + y0[q] + z0[q] + b1v[q]);
      acc[q + 4] += gelu_f(x1[q] + y1[q] + z1[q] + b1v[q + 4]);
    }
  }
  u16x8 o;
  #pragma unroll
  for (int q = 0; q < 8; ++q) o[q] = f2bf(acc[q]);
  *(u16x8*)&HSb[(size_t)node * 512 + c0] = o;
}

// ---- gemm2 MFMA with register prefetch: agg = HSb @ W2 + cnt*b2 + pos[s] ----
__global__ __launch_bounds__(256) void gemm2_k(
    const u16* __restrict__ HSb, const u16* __restrict__ W2T,
    const void* __restrict__ b2, const void* __restrict__ pos,
    const int* __restrict__ counts, float* __restrict__ agg,
    const int* __restrict__ flags)
{
  const int fF = flags[0];
  __shared__ u16 As[64 * 40];
  __shared__ u16 Bs[64 * 40];
  const int tid = threadIdx.x;
  const int lane = tid & 63;
  const int wave = tid >> 6;
  const int wm = (wave & 1) * 32;
  const int wn = (wave >> 1) * 32;
  const int r = tid >> 2;
  const int c8 = (tid & 3) * 8;
  const int n0 = blockIdx.y * 64;

  const u16* asrc0 = HSb + (size_t)(blockIdx.x * 64 + r) * 512 + c8;
  const u16* bsrc  = W2T + (size_t)(n0 + r) * 512 + c8;

  f32x4 acc[2][2] = {{{0.f,0.f,0.f,0.f},{0.f,0.f,0.f,0.f}},
                     {{0.f,0.f,0.f,0.f},{0.f,0.f,0.f,0.f}}};
  const int lrow = lane & 15;
  const int qk = (lane >> 4) * 8;

  u16x8 avc = *(const u16x8*)(asrc0);
  u16x8 bvc = *(const u16x8*)(bsrc);
  for (int kt = 0; kt < 16; ++kt) {
    *(u16x8*)&As[r * 40 + c8] = avc;
    *(u16x8*)&Bs[r * 40 + c8] = bvc;
    __syncthreads();
    const int k1 = (kt + 1 < 16) ? (kt + 1) * 32 : 0;
    u16x8 avn = *(const u16x8*)(asrc0 + k1);
    u16x8 bvn = *(const u16x8*)(bsrc + k1);
    bf16x8 af0 = *(const bf16x8*)&As[(wm + lrow) * 40 + qk];
    bf16x8 af1 = *(const bf16x8*)&As[(wm + 16 + lrow) * 40 + qk];
    bf16x8 bf0 = *(const bf16x8*)&Bs[(wn + lrow) * 40 + qk];
    bf16x8 bf1 = *(const bf16x8*)&Bs[(wn + 16 + lrow) * 40 + qk];
    acc[0][0] = __builtin_amdgcn_mfma_f32_16x16x32_bf16(af0, bf0, acc[0][0], 0, 0, 0);
    acc[0][1] = __builtin_amdgcn_mfma_f32_16x16x32_bf16(af0, bf1, acc[0][1], 0, 0, 0);
    acc[1][0] = __builtin_amdgcn_mfma_f32_16x16x32_bf16(af1, bf0, acc[1][0], 0, 0, 0);
    acc[1][1] = __builtin_amdgcn_mfma_f32_16x16x32_bf16(af1, bf1, acc[1][1], 0, 0, 0);
    __syncthreads();
    avc = avn; bvc = bvn;
  }
  const int quad = lane >> 4;
  for (int j = 0; j < 2; ++j) {
    const int col = n0 + wn + j * 16 + lrow;
    const float b2v = ldf(b2, col, fF);
    for (int i = 0; i < 2; ++i) {
      const int row = blockIdx.x * 64 + wm + i * 16 + quad * 4;
      for (int rg = 0; rg < 4; ++rg) {
        const int s = (row + rg) & 511;
        agg[(size_t)(row + rg) * 256 + col] =
            acc[i][j][rg] + (float)counts[row + rg] * b2v
            + ldf(pos, (size_t)s * 256 + col, fF);
      }
    }
  }
}

// ---- ln_pool ----
__global__ __launch_bounds__(256) void ln_pool_k(
    const float* __restrict__ agg, const void* __restrict__ g,
    const void* __restrict__ bta, float* __restrict__ pooled,
    const int* __restrict__ flags)
{
  const int fF = flags[0];
  __shared__ float red[4][256];
  const int b = blockIdx.x >> 3, c = blockIdx.x & 7;
  const int w = threadIdx.x >> 6, lane = threadIdx.x & 63;
  const int d0 = lane * 4;
  float g4[4], bt4[4];
  #pragma unroll
  for (int i = 0; i < 4; ++i) {
    g4[i] = ldf(g, d0 + i, fF);
    bt4[i] = ldf(bta, d0 + i, fF);
  }
  float pacc[4] = {};
  for (int r = 0; r < 16; ++r) {
    const int row = b * 512 + c * 64 + w * 16 + r;
    f32x4 a = *(const f32x4*)&agg[(size_t)row * 256 + d0];
    float sum = a[0] + a[1] + a[2] + a[3];
    float sq = a[0]*a[0] + a[1]*a[1] + a[2]*a[2] + a[3]*a[3];
    for (int o = 32; o; o >>= 1) {
      sum += __shfl_xor(sum, o, 64);
      sq  += __shfl_xor(sq, o, 64);
    }
    const float mean = sum * (1.0f / 256.0f);
    const float var = sq * (1.0f / 256.0f) - mean * mean;
    const float rs = rsqrtf(var + 1e-5f);
    #pragma unroll
    for (int i = 0; i < 4; ++i)
      pacc[i] += (a[i] - mean) * rs * g4[i] + bt4[i];
  }
  #pragma unroll
  for (int i = 0; i < 4; ++i) red[w][d0 + i] = pacc[i];
  __syncthreads();
  if (w == 0) {
    #pragma unroll
    for (int i = 0; i < 4; ++i) {
      const float v = red[0][d0+i] + red[1][d0+i] + red[2][d0+i] + red[3][d0+i];
      atomicAdd(&pooled[b * 256 + d0 + i], v * (1.0f / 512.0f));
    }
  }
}

// ---- head MLPs ----
__global__ __launch_bounds__(256) void mlp1_k(const float* __restrict__ pooled,
    const void* __restrict__ Wl1, const void* __restrict__ bl1,
    float* __restrict__ hid, const int* __restrict__ flags)
{
  const int fF = flags[0];
  const int gid = blockIdx.x * 256 + threadIdx.x;
  const int oid = gid >> 2, sub = gid & 3;
  const int b = oid >> 9, n = oid & 511;
  const float* pr = pooled + b * 256;
  float s = 0.f;
  for (int i = 0; i < 64; ++i) {
    const int k = sub + 4 * i;
    s += pr[k] * ldf(Wl1, (size_t)k * 512 + n, fF);
  }
  s += __shfl_xor(s, 1, 64);
  s += __shfl_xor(s, 2, 64);
  if (sub == 0) hid[oid] = gelu_f(s + ldf(bl1, n, fF));
}
__global__ __launch_bounds__(256) void mlp2_k(const float* __restrict__ hid,
    const void* __restrict__ Wl2, const void* __restrict__ bl2,
    float* __restrict__ outp, const int* __restrict__ flags)
{
  const int fF = flags[0];
  const int gid = blockIdx.x * 256 + threadIdx.x;
  const int oid = gid >> 3, sub = gid & 7;
  const int b = oid >> 9, n = oid & 511;
  const float* hr = hid + b * 512;
  float s = 0.f;
  for (int i = 0; i < 64; ++i) {
    const int k = sub + 8 * i;
    s += hr[k] * ldf(Wl2, (size_t)k * 512 + n, fF);
  }
  s += __shfl_xor(s, 1, 64);
  s += __shfl_xor(s, 2, 64);
  s += __shfl_xor(s, 4, 64);
  if (sub == 0) outp[oid] = s + ldf(bl2, n, fF);
}

extern "C" void kernel_launch(void* const* d_in, const int* in_sizes, int n_in,
                              void* d_out, int out_size, void* d_ws, size_t ws_size,
                              hipStream_t stream)
{
  const void* a0   = d_in[0];
  const void* a1   = d_in[1];
  const void* pred = d_in[2];
  const void* role = d_in[3];
  const void* pos  = d_in[5];
  const void* pe   = d_in[6];
  const void* re   = d_in[7];
  const void* W1   = d_in[8];
  const void* b1   = d_in[9];
  const void* W2   = d_in[10];
  const void* b2   = d_in[11];
  const void* lng  = d_in[12];
  const void* lnb  = d_in[13];
  const void* Wl1  = d_in[14];
  const void* bl1  = d_in[15];
  const void* Wl2  = d_in[16];
  const void* bl2  = d_in[17];

  static const int EXP[18] = {32768, 32768, 32768, 32768, 1,
                              131072, 2048, 2048, 393216, 512,
                              131072, 256, 256, 256, 131072, 512, 262144, 512};
  long long code = 0;
  if (n_in != 18) code = 1000000 + (long long)n_in * 16384;
  if (!code)
    for (int i = 0; i < 18; ++i)
      if (in_sizes[i] != EXP[i]) { code = 3000000 + (long long)i * 65536; break; }
  if (!code && out_size != 8192) code = 9000000;

  size_t o = 0;
  const size_t offFlags = o; o += 256;
  const size_t offPool  = o; o += 16384;
  const size_t offHid   = o; o += 32768;
  const size_t offW2T   = o; o += (size_t)256 * 512 * 2;
  const size_t offPA    = o; o += (size_t)512 * 512 * 4;
  const size_t offPC    = o; o += (size_t)512 * 512 * 4;   // contiguous with PA
  const size_t offPE8   = o; o += (size_t)8 * 512 * 4;
  const size_t offRE8   = o; o += (size_t)8 * 512 * 4;     // contiguous with PE8
  const size_t offCnt   = o; o += (size_t)NN * 4;
  const size_t offOff   = o; o += (size_t)NN * 4;
  const size_t offCur   = o; o += (size_t)NN * 4;
  const size_t offList  = o; o += (size_t)M_ * 4;
  const size_t offHSb   = o; o += (size_t)NN * 512 * 2;
  const size_t offAgg   = o; o += (size_t)NN * 256 * 4;
  if (!code && o > ws_size)
    code = 5000000 + (long long)((ws_size >> 20) & 255) * 32768;
  if (code) {
    diag_k<<<(out_size + 255) / 256, 256, 0, stream>>>((float*)d_out, out_size, (float)code);
    return;
  }

  char* w = (char*)d_ws;
  int* flags    = (int*)(w + offFlags);
  float* pooled = (float*)(w + offPool);
  float* hid    = (float*)(w + offHid);
  u16* W2T      = (u16*)(w + offW2T);
  float* PA     = (float*)(w + offPA);
  float* PC     = (float*)(w + offPC);
  float* PE8    = (float*)(w + offPE8);
  float* RE8    = (float*)(w + offRE8);
  int* counts   = (int*)(w + offCnt);
  int* offsets  = (int*)(w + offOff);
  int* cursor   = (int*)(w + offCur);
  int* plist    = (int*)(w + offList);
  u16* HSb      = (u16*)(w + offHSb);
  float* agg    = (float*)(w + offAgg);

  init_k<<<20, 256, 0, stream>>>(pooled, counts, PE8,
                                 (const unsigned int*)lng,
                                 (const int*)a0, (const int*)a1, flags);
  prep_k<<<672, 256, 0, stream>>>(a0, a1, pred, W2, pos, W1, pe, re,
                                  W2T, PA, PC, PE8, RE8, counts, flags);
  scan_k<<<1, 256, 0, stream>>>(counts, offsets, cursor);
  fill_k<<<M_ / 256, 256, 0, stream>>>(a0, a1, pred, role, cursor, plist, flags);
  nodesum_k<<<NN / 4, 256, 0, stream>>>(PA, PC, PE8, RE8, b1,
                                        plist, offsets, counts, HSb, flags);
  gemm2_k<<<dim3(NN / 64, 4), 256, 0, stream>>>(HSb, W2T, b2, pos, counts, agg, flags);
  ln_pool_k<<<128, 256, 0, stream>>>(agg, lng, lnb, pooled, flags);
  mlp1_k<<<128, 256, 0, stream>>>(pooled, Wl1, bl1, hid, flags);
  mlp2_k<<<256, 256, 0, stream>>>(hid, Wl2, bl2, (float*)d_out, flags);
}